// Round 2
// baseline (2715.306 us; speedup 1.0000x reference)
//
#include <hip/hip_runtime.h>

// Guided filter, B=2, H=W=1024, C=3, K=4, R=16, EPS=0.01.
// gf(x) = Vblur33(Hblur33(x)) - x  (separable Gaussian, center tap removed),
// N(y,x) = rowW(x)*colW(y) - 1 computed in closed form per pixel.
// Workspace requirement: 50 planes * 4 MiB = 209,715,200 bytes.

#define HH 1024
#define WW 1024
#define HWSZ (HH * WW)
#define RR 16
#define NT 33
#define EPSF 0.01f
#define VT 32  // rows per block in vertical-blur kernels

__device__ __forceinline__ void make_wg(float wg[NT]) {
#pragma unroll
  for (int i = 0; i < NT; ++i) {
    const float d = (float)(i - RR);
    wg[i] = __expf(d * d * (-1.0f / 32.0f));  // exp(-0.5*d^2/theta^2), theta=4
  }
}

__device__ __forceinline__ float wsum(const float wg[NT]) {
  float s = 0.0f;
#pragma unroll
  for (int i = 0; i < NT; ++i) s += wg[i];
  return s;
}

// edge-aware 1D window weight at coordinate u in [0, n)
__device__ __forceinline__ float win_w(const float wg[NT], float S, int u, int n) {
  if (u >= RR && u < n - RR) return S;
  float w = 0.0f;
#pragma unroll
  for (int i = 0; i < NT; ++i) {
    const int uu = u - RR + i;
    if (uu >= 0 && uu < n) w += wg[i];
  }
  return w;
}

// ---------------------------------------------------------------------------
// K1: products + horizontal blur. Grid (W/256, H), block 256.
// Writes 25 planes: [0..2]=I, [3..6]=p, [7..18]=I_c*p_k (c*4+k), [19..24]=I_cI_c' sym
// ---------------------------------------------------------------------------
__global__ __launch_bounds__(256) void k_prod_hblur(const float* __restrict__ I,
                                                    const float* __restrict__ P,
                                                    float* __restrict__ HB) {
  __shared__ float sI[3][288];
  __shared__ float sp[4][288];
  const int tid = threadIdx.x;
  const int y = blockIdx.y;
  const int x0 = blockIdx.x * 256;
  {
    const int base = (y * WW + (x0 - RR)) * 3;
    for (int idx = tid; idx < 288 * 3; idx += 256) {
      const int xi = idx / 3;
      const int c = idx - xi * 3;
      const int xx = x0 - RR + xi;
      sI[c][xi] = (xx >= 0 && xx < WW) ? I[base + idx] : 0.0f;
    }
  }
  {
    const int base = (y * WW + (x0 - RR)) * 4;
    for (int idx = tid; idx < 288 * 4; idx += 256) {
      const int xi = idx >> 2;
      const int c = idx & 3;
      const int xx = x0 - RR + xi;
      sp[c][xi] = (xx >= 0 && xx < WW) ? P[base + idx] : 0.0f;
    }
  }
  __syncthreads();

  float wg[NT];
  make_wg(wg);
  float acc[25];
#pragma unroll
  for (int j = 0; j < 25; ++j) acc[j] = 0.0f;

#pragma unroll
  for (int dx = 0; dx < NT; ++dx) {
    const float w = wg[dx];
    const float i0 = sI[0][tid + dx], i1 = sI[1][tid + dx], i2 = sI[2][tid + dx];
    const float p0 = sp[0][tid + dx], p1 = sp[1][tid + dx];
    const float p2 = sp[2][tid + dx], p3 = sp[3][tid + dx];
    const float wi0 = w * i0, wi1 = w * i1, wi2 = w * i2;
    const float wp0 = w * p0, wp1 = w * p1, wp2 = w * p2, wp3 = w * p3;
    acc[0] += wi0; acc[1] += wi1; acc[2] += wi2;
    acc[3] += wp0; acc[4] += wp1; acc[5] += wp2; acc[6] += wp3;
    acc[7]  += i0 * wp0; acc[8]  += i0 * wp1; acc[9]  += i0 * wp2; acc[10] += i0 * wp3;
    acc[11] += i1 * wp0; acc[12] += i1 * wp1; acc[13] += i1 * wp2; acc[14] += i1 * wp3;
    acc[15] += i2 * wp0; acc[16] += i2 * wp1; acc[17] += i2 * wp2; acc[18] += i2 * wp3;
    acc[19] += wi0 * i0; acc[20] += wi0 * i1; acc[21] += wi0 * i2;
    acc[22] += wi1 * i1; acc[23] += wi1 * i2; acc[24] += wi2 * i2;
  }
  const int o = y * WW + x0 + tid;
#pragma unroll
  for (int ch = 0; ch < 25; ++ch) HB[ch * HWSZ + o] = acc[ch];
}

// ---------------------------------------------------------------------------
// K2: vertical blur (VT=32 rolling, one plane/block) + center subtract + /N
//     -> 25 mean planes.  Grid (W/256, H/VT, 25), block 256.
// ---------------------------------------------------------------------------
__global__ __launch_bounds__(256) void k_vblur25(const float* __restrict__ HB,
                                                 const float* __restrict__ I,
                                                 const float* __restrict__ P,
                                                 float* __restrict__ M) {
  const int tid = threadIdx.x;
  const int ch = blockIdx.z;
  const int x = blockIdx.x * 256 + tid;
  const int y0 = blockIdx.y * VT;
  float wg[NT];
  make_wg(wg);
  const float S = wsum(wg);

  float acc[VT];
#pragma unroll
  for (int t = 0; t < VT; ++t) acc[t] = 0.0f;
  const float* src = HB + ch * HWSZ;
#pragma unroll
  for (int r = 0; r < VT + 2 * RR; ++r) {
    const int yy = y0 - RR + r;
    float v = 0.0f;
    if (yy >= 0 && yy < HH) v = src[yy * WW + x];
#pragma unroll
    for (int t = 0; t < VT; ++t) {
      const int dy = r - t;
      if (dy >= 0 && dy < NT) acc[t] += wg[dy] * v;
    }
  }
  const float rowW = win_w(wg, S, x, WW);

  // channel -> center-value decode (wave-uniform)
  int kind, cA, cB;
  if (ch < 3)       { kind = 0; cA = ch;            cB = 0; }
  else if (ch < 7)  { kind = 1; cA = ch - 3;        cB = 0; }
  else if (ch < 19) { kind = 2; cA = (ch - 7) >> 2; cB = (ch - 7) & 3; }
  else {
    kind = 3;
    const int j = ch - 19;  // (0,0)(0,1)(0,2)(1,1)(1,2)(2,2)
    cA = (j < 3) ? 0 : ((j < 5) ? 1 : 2);
    cB = (j == 0) ? 0 : (j == 1 ? 1 : (j == 2 ? 2 : (j == 3 ? 1 : 2)));
  }
#pragma unroll
  for (int t = 0; t < VT; ++t) {
    const int y = y0 + t;
    const float colW = win_w(wg, S, y, HH);
    const int pix = y * WW + x;
    float center;
    if (kind == 0)      center = I[pix * 3 + cA];
    else if (kind == 1) center = P[pix * 4 + cA];
    else if (kind == 2) center = I[pix * 3 + cA] * P[pix * 4 + cB];
    else                center = I[pix * 3 + cA] * I[pix * 3 + cB];
    const float invN = 1.0f / (rowW * colW - 1.0f);
    M[ch * HWSZ + pix] = (acc[t] - center) * invN;
  }
}

// ---------------------------------------------------------------------------
// K3: pointwise 3x3 SPD solve with 4 RHS -> 16 planes (a: c*4+k, b: 12+k).
// Grid (HW/256), block 256.
// ---------------------------------------------------------------------------
__global__ __launch_bounds__(256) void k_solve(const float* __restrict__ M,
                                               float* __restrict__ AB) {
  const int i = blockIdx.x * 256 + threadIdx.x;
  const float mI0 = M[i], mI1 = M[HWSZ + i], mI2 = M[2 * HWSZ + i];
  float mp[4];
#pragma unroll
  for (int k = 0; k < 4; ++k) mp[k] = M[(3 + k) * HWSZ + i];
  float cov[12];
#pragma unroll
  for (int j = 0; j < 12; ++j) cov[j] = M[(7 + j) * HWSZ + i];
#pragma unroll
  for (int k = 0; k < 4; ++k) {
    cov[k]     -= mI0 * mp[k];
    cov[4 + k] -= mI1 * mp[k];
    cov[8 + k] -= mI2 * mp[k];
  }
  const float A00 = M[19 * HWSZ + i] - mI0 * mI0 + EPSF;
  const float A01 = M[20 * HWSZ + i] - mI0 * mI1;
  const float A02 = M[21 * HWSZ + i] - mI0 * mI2;
  const float A11 = M[22 * HWSZ + i] - mI1 * mI1 + EPSF;
  const float A12 = M[23 * HWSZ + i] - mI1 * mI2;
  const float A22 = M[24 * HWSZ + i] - mI2 * mI2 + EPSF;
  const float c00 = A11 * A22 - A12 * A12;
  const float c01 = A02 * A12 - A01 * A22;
  const float c02 = A01 * A12 - A02 * A11;
  const float det = A00 * c00 + A01 * c01 + A02 * c02;
  const float idet = 1.0f / det;
  const float i00 = c00 * idet, i01 = c01 * idet, i02 = c02 * idet;
  const float i11 = (A00 * A22 - A02 * A02) * idet;
  const float i12 = (A01 * A02 - A00 * A12) * idet;
  const float i22 = (A00 * A11 - A01 * A01) * idet;
#pragma unroll
  for (int k = 0; k < 4; ++k) {
    const float a0 = i00 * cov[k] + i01 * cov[4 + k] + i02 * cov[8 + k];
    const float a1 = i01 * cov[k] + i11 * cov[4 + k] + i12 * cov[8 + k];
    const float a2 = i02 * cov[k] + i12 * cov[4 + k] + i22 * cov[8 + k];
    AB[k * HWSZ + i] = a0;
    AB[(4 + k) * HWSZ + i] = a1;
    AB[(8 + k) * HWSZ + i] = a2;
    AB[(12 + k) * HWSZ + i] = mp[k] - (a0 * mI0 + a1 * mI1 + a2 * mI2);
  }
}

// ---------------------------------------------------------------------------
// K4: plain horizontal blur of 16 planes. Grid (W/256, H, 16), block 256.
// ---------------------------------------------------------------------------
__global__ __launch_bounds__(256) void k_hblur16(const float* __restrict__ AB,
                                                 float* __restrict__ HB) {
  __shared__ float s[288];
  const int tid = threadIdx.x;
  const int ch = blockIdx.z;
  const int y = blockIdx.y;
  const int x0 = blockIdx.x * 256;
  const float* src = AB + ch * HWSZ + y * WW;
  for (int idx = tid; idx < 288; idx += 256) {
    const int xx = x0 - RR + idx;
    s[idx] = (xx >= 0 && xx < WW) ? src[xx] : 0.0f;
  }
  __syncthreads();
  float wg[NT];
  make_wg(wg);
  float a = 0.0f;
#pragma unroll
  for (int dx = 0; dx < NT; ++dx) a += wg[dx] * s[tid + dx];
  HB[ch * HWSZ + y * WW + x0 + tid] = a;
}

// ---------------------------------------------------------------------------
// K5a: vertical blur of 16 planes (VT=32 rolling, one plane/block) +
//      center subtract (in-place on AB) + /N.  AB plane becomes mean plane.
//      Grid (W/256, H/VT, 16), block 256.
//      In-place is safe: each thread reads AB[ch][pix] then writes the same
//      address; no other block touches that address.
// ---------------------------------------------------------------------------
__global__ __launch_bounds__(256) void k_vblur16(const float* __restrict__ HB,
                                                 float* __restrict__ AB) {
  const int tid = threadIdx.x;
  const int ch = blockIdx.z;
  const int x = blockIdx.x * 256 + tid;
  const int y0 = blockIdx.y * VT;
  float wg[NT];
  make_wg(wg);
  const float S = wsum(wg);

  float acc[VT];
#pragma unroll
  for (int t = 0; t < VT; ++t) acc[t] = 0.0f;
  const float* src = HB + ch * HWSZ;
#pragma unroll
  for (int r = 0; r < VT + 2 * RR; ++r) {
    const int yy = y0 - RR + r;
    float v = 0.0f;
    if (yy >= 0 && yy < HH) v = src[yy * WW + x];
#pragma unroll
    for (int t = 0; t < VT; ++t) {
      const int dy = r - t;
      if (dy >= 0 && dy < NT) acc[t] += wg[dy] * v;
    }
  }
  const float rowW = win_w(wg, S, x, WW);
  float* dst = AB + ch * HWSZ;
#pragma unroll
  for (int t = 0; t < VT; ++t) {
    const int y = y0 + t;
    const float colW = win_w(wg, S, y, HH);
    const int pix = y * WW + x;
    const float invN = 1.0f / (rowW * colW - 1.0f);
    const float center = dst[pix];
    dst[pix] = (acc[t] - center) * invN;
  }
}

// ---------------------------------------------------------------------------
// K5b: pointwise combine q_k = sum_c mean_a[c,k]*I_c + mean_b[k].
//      Grid (HW/256), block 256.
// ---------------------------------------------------------------------------
__global__ __launch_bounds__(256) void k_combine(const float* __restrict__ M2,
                                                 const float* __restrict__ I,
                                                 float* __restrict__ out) {
  const int i = blockIdx.x * 256 + threadIdx.x;
  float m[16];
#pragma unroll
  for (int ch = 0; ch < 16; ++ch) m[ch] = M2[ch * HWSZ + i];
  const float i0 = I[i * 3], i1 = I[i * 3 + 1], i2 = I[i * 3 + 2];
  float4 q;
  q.x = m[0] * i0 + m[4] * i1 + m[8] * i2 + m[12];
  q.y = m[1] * i0 + m[5] * i1 + m[9] * i2 + m[13];
  q.z = m[2] * i0 + m[6] * i1 + m[10] * i2 + m[14];
  q.w = m[3] * i0 + m[7] * i1 + m[11] * i2 + m[15];
  *reinterpret_cast<float4*>(out + (size_t)i * 4) = q;
}

extern "C" void kernel_launch(void* const* d_in, const int* in_sizes, int n_in,
                              void* d_out, int out_size, void* d_ws, size_t ws_size,
                              hipStream_t stream) {
  const float* I = (const float*)d_in[0];
  const float* P = (const float*)d_in[1];
  float* out = (float*)d_out;
  float* buf0 = (float*)d_ws;              // 25 planes
  float* buf1 = buf0 + 25 * (size_t)HWSZ;  // 25 planes

  for (int b = 0; b < 2; ++b) {
    const float* Ib = I + (size_t)b * HWSZ * 3;
    const float* Pb = P + (size_t)b * HWSZ * 4;
    float* outb = out + (size_t)b * HWSZ * 4;

    k_prod_hblur<<<dim3(WW / 256, HH), dim3(256), 0, stream>>>(Ib, Pb, buf0);
    k_vblur25<<<dim3(WW / 256, HH / VT, 25), dim3(256), 0, stream>>>(buf0, Ib, Pb, buf1);
    k_solve<<<dim3(HWSZ / 256), dim3(256), 0, stream>>>(buf1, buf0);
    k_hblur16<<<dim3(WW / 256, HH, 16), dim3(256), 0, stream>>>(buf0, buf1);
    k_vblur16<<<dim3(WW / 256, HH / VT, 16), dim3(256), 0, stream>>>(buf1, buf0);
    k_combine<<<dim3(HWSZ / 256), dim3(256), 0, stream>>>(buf0, Ib, outb);
  }
}

// Round 3
// 539.671 us; speedup vs baseline: 5.0314x; 5.0314x over previous
//
#include <hip/hip_runtime.h>

// Guided filter, B=2, H=W=1024, C=3, K=4, R=16, EPS=0.01.
// gf(x) = Vblur33(Hblur33(x)) - x  (separable Gaussian, center tap removed),
// N(y,x) = rowW(x)*colW(y) - 1 computed in closed form per pixel.
// Workspace requirement: 50 planes * 4 MiB = 209,715,200 bytes.
//
// VT=8 for vertical blurs: VT=32 made the unrolled rolling loop exceed the
// compiler's unroll budget -> runtime-indexed acc[]/wg[] -> scratch spill
// (R2: VGPR=44, 2x WRITE_SIZE, 780us/dispatch). VT=8 is known-good codegen.

#define HH 1024
#define WW 1024
#define HWSZ (HH * WW)
#define RR 16
#define NT 33
#define EPSF 0.01f
#define VT 8  // rows per block in vertical-blur kernels (do NOT raise: spills)

__device__ __forceinline__ void make_wg(float wg[NT]) {
#pragma unroll
  for (int i = 0; i < NT; ++i) {
    const float d = (float)(i - RR);
    wg[i] = __expf(d * d * (-1.0f / 32.0f));  // exp(-0.5*d^2/theta^2), theta=4
  }
}

__device__ __forceinline__ float wsum(const float wg[NT]) {
  float s = 0.0f;
#pragma unroll
  for (int i = 0; i < NT; ++i) s += wg[i];
  return s;
}

// edge-aware 1D window weight at coordinate u in [0, n)
__device__ __forceinline__ float win_w(const float wg[NT], float S, int u, int n) {
  if (u >= RR && u < n - RR) return S;
  float w = 0.0f;
#pragma unroll
  for (int i = 0; i < NT; ++i) {
    const int uu = u - RR + i;
    if (uu >= 0 && uu < n) w += wg[i];
  }
  return w;
}

// ---------------------------------------------------------------------------
// K1: products + horizontal blur. Grid (W/256, H), block 256.
// Writes 25 planes: [0..2]=I, [3..6]=p, [7..18]=I_c*p_k (c*4+k), [19..24]=I_cI_c' sym
// ---------------------------------------------------------------------------
__global__ __launch_bounds__(256) void k_prod_hblur(const float* __restrict__ I,
                                                    const float* __restrict__ P,
                                                    float* __restrict__ HB) {
  __shared__ float sI[3][288];
  __shared__ float sp[4][288];
  const int tid = threadIdx.x;
  const int y = blockIdx.y;
  const int x0 = blockIdx.x * 256;
  {
    const int base = (y * WW + (x0 - RR)) * 3;
    for (int idx = tid; idx < 288 * 3; idx += 256) {
      const int xi = idx / 3;
      const int c = idx - xi * 3;
      const int xx = x0 - RR + xi;
      sI[c][xi] = (xx >= 0 && xx < WW) ? I[base + idx] : 0.0f;
    }
  }
  {
    const int base = (y * WW + (x0 - RR)) * 4;
    for (int idx = tid; idx < 288 * 4; idx += 256) {
      const int xi = idx >> 2;
      const int c = idx & 3;
      const int xx = x0 - RR + xi;
      sp[c][xi] = (xx >= 0 && xx < WW) ? P[base + idx] : 0.0f;
    }
  }
  __syncthreads();

  float wg[NT];
  make_wg(wg);
  float acc[25];
#pragma unroll
  for (int j = 0; j < 25; ++j) acc[j] = 0.0f;

#pragma unroll
  for (int dx = 0; dx < NT; ++dx) {
    const float w = wg[dx];
    const float i0 = sI[0][tid + dx], i1 = sI[1][tid + dx], i2 = sI[2][tid + dx];
    const float p0 = sp[0][tid + dx], p1 = sp[1][tid + dx];
    const float p2 = sp[2][tid + dx], p3 = sp[3][tid + dx];
    const float wi0 = w * i0, wi1 = w * i1, wi2 = w * i2;
    const float wp0 = w * p0, wp1 = w * p1, wp2 = w * p2, wp3 = w * p3;
    acc[0] += wi0; acc[1] += wi1; acc[2] += wi2;
    acc[3] += wp0; acc[4] += wp1; acc[5] += wp2; acc[6] += wp3;
    acc[7]  += i0 * wp0; acc[8]  += i0 * wp1; acc[9]  += i0 * wp2; acc[10] += i0 * wp3;
    acc[11] += i1 * wp0; acc[12] += i1 * wp1; acc[13] += i1 * wp2; acc[14] += i1 * wp3;
    acc[15] += i2 * wp0; acc[16] += i2 * wp1; acc[17] += i2 * wp2; acc[18] += i2 * wp3;
    acc[19] += wi0 * i0; acc[20] += wi0 * i1; acc[21] += wi0 * i2;
    acc[22] += wi1 * i1; acc[23] += wi1 * i2; acc[24] += wi2 * i2;
  }
  const int o = y * WW + x0 + tid;
#pragma unroll
  for (int ch = 0; ch < 25; ++ch) HB[ch * HWSZ + o] = acc[ch];
}

// ---------------------------------------------------------------------------
// K2: vertical blur (VT=8 rolling, one plane/block) + center subtract + /N
//     -> 25 mean planes.  Grid (W/256, H/VT, 25), block 256.
// ---------------------------------------------------------------------------
__global__ __launch_bounds__(256) void k_vblur25(const float* __restrict__ HB,
                                                 const float* __restrict__ I,
                                                 const float* __restrict__ P,
                                                 float* __restrict__ M) {
  const int tid = threadIdx.x;
  const int ch = blockIdx.z;
  const int x = blockIdx.x * 256 + tid;
  const int y0 = blockIdx.y * VT;
  float wg[NT];
  make_wg(wg);
  const float S = wsum(wg);

  float acc[VT];
#pragma unroll
  for (int t = 0; t < VT; ++t) acc[t] = 0.0f;
  const float* src = HB + ch * HWSZ;
#pragma unroll
  for (int r = 0; r < VT + 2 * RR; ++r) {
    const int yy = y0 - RR + r;
    float v = 0.0f;
    if (yy >= 0 && yy < HH) v = src[yy * WW + x];
#pragma unroll
    for (int t = 0; t < VT; ++t) {
      const int dy = r - t;
      if (dy >= 0 && dy < NT) acc[t] += wg[dy] * v;
    }
  }
  const float rowW = win_w(wg, S, x, WW);

  // channel -> center-value decode (wave-uniform)
  int kind, cA, cB;
  if (ch < 3)       { kind = 0; cA = ch;            cB = 0; }
  else if (ch < 7)  { kind = 1; cA = ch - 3;        cB = 0; }
  else if (ch < 19) { kind = 2; cA = (ch - 7) >> 2; cB = (ch - 7) & 3; }
  else {
    kind = 3;
    const int j = ch - 19;  // (0,0)(0,1)(0,2)(1,1)(1,2)(2,2)
    cA = (j < 3) ? 0 : ((j < 5) ? 1 : 2);
    cB = (j == 0) ? 0 : (j == 1 ? 1 : (j == 2 ? 2 : (j == 3 ? 1 : 2)));
  }
#pragma unroll
  for (int t = 0; t < VT; ++t) {
    const int y = y0 + t;
    const float colW = win_w(wg, S, y, HH);
    const int pix = y * WW + x;
    float center;
    if (kind == 0)      center = I[pix * 3 + cA];
    else if (kind == 1) center = P[pix * 4 + cA];
    else if (kind == 2) center = I[pix * 3 + cA] * P[pix * 4 + cB];
    else                center = I[pix * 3 + cA] * I[pix * 3 + cB];
    const float invN = 1.0f / (rowW * colW - 1.0f);
    M[ch * HWSZ + pix] = (acc[t] - center) * invN;
  }
}

// ---------------------------------------------------------------------------
// K3: pointwise 3x3 SPD solve with 4 RHS -> 16 planes (a: c*4+k, b: 12+k).
// Grid (HW/256), block 256.
// ---------------------------------------------------------------------------
__global__ __launch_bounds__(256) void k_solve(const float* __restrict__ M,
                                               float* __restrict__ AB) {
  const int i = blockIdx.x * 256 + threadIdx.x;
  const float mI0 = M[i], mI1 = M[HWSZ + i], mI2 = M[2 * HWSZ + i];
  float mp[4];
#pragma unroll
  for (int k = 0; k < 4; ++k) mp[k] = M[(3 + k) * HWSZ + i];
  float cov[12];
#pragma unroll
  for (int j = 0; j < 12; ++j) cov[j] = M[(7 + j) * HWSZ + i];
#pragma unroll
  for (int k = 0; k < 4; ++k) {
    cov[k]     -= mI0 * mp[k];
    cov[4 + k] -= mI1 * mp[k];
    cov[8 + k] -= mI2 * mp[k];
  }
  const float A00 = M[19 * HWSZ + i] - mI0 * mI0 + EPSF;
  const float A01 = M[20 * HWSZ + i] - mI0 * mI1;
  const float A02 = M[21 * HWSZ + i] - mI0 * mI2;
  const float A11 = M[22 * HWSZ + i] - mI1 * mI1 + EPSF;
  const float A12 = M[23 * HWSZ + i] - mI1 * mI2;
  const float A22 = M[24 * HWSZ + i] - mI2 * mI2 + EPSF;
  const float c00 = A11 * A22 - A12 * A12;
  const float c01 = A02 * A12 - A01 * A22;
  const float c02 = A01 * A12 - A02 * A11;
  const float det = A00 * c00 + A01 * c01 + A02 * c02;
  const float idet = 1.0f / det;
  const float i00 = c00 * idet, i01 = c01 * idet, i02 = c02 * idet;
  const float i11 = (A00 * A22 - A02 * A02) * idet;
  const float i12 = (A01 * A02 - A00 * A12) * idet;
  const float i22 = (A00 * A11 - A01 * A01) * idet;
#pragma unroll
  for (int k = 0; k < 4; ++k) {
    const float a0 = i00 * cov[k] + i01 * cov[4 + k] + i02 * cov[8 + k];
    const float a1 = i01 * cov[k] + i11 * cov[4 + k] + i12 * cov[8 + k];
    const float a2 = i02 * cov[k] + i12 * cov[4 + k] + i22 * cov[8 + k];
    AB[k * HWSZ + i] = a0;
    AB[(4 + k) * HWSZ + i] = a1;
    AB[(8 + k) * HWSZ + i] = a2;
    AB[(12 + k) * HWSZ + i] = mp[k] - (a0 * mI0 + a1 * mI1 + a2 * mI2);
  }
}

// ---------------------------------------------------------------------------
// K4: plain horizontal blur of 16 planes. Grid (W/256, H, 16), block 256.
// ---------------------------------------------------------------------------
__global__ __launch_bounds__(256) void k_hblur16(const float* __restrict__ AB,
                                                 float* __restrict__ HB) {
  __shared__ float s[288];
  const int tid = threadIdx.x;
  const int ch = blockIdx.z;
  const int y = blockIdx.y;
  const int x0 = blockIdx.x * 256;
  const float* src = AB + ch * HWSZ + y * WW;
  for (int idx = tid; idx < 288; idx += 256) {
    const int xx = x0 - RR + idx;
    s[idx] = (xx >= 0 && xx < WW) ? src[xx] : 0.0f;
  }
  __syncthreads();
  float wg[NT];
  make_wg(wg);
  float a = 0.0f;
#pragma unroll
  for (int dx = 0; dx < NT; ++dx) a += wg[dx] * s[tid + dx];
  HB[ch * HWSZ + y * WW + x0 + tid] = a;
}

// ---------------------------------------------------------------------------
// K5a: vertical blur of 16 planes (VT=8 rolling, one plane/block) +
//      center subtract (in-place on AB) + /N.  AB plane becomes mean plane.
//      Grid (W/256, H/VT, 16), block 256.
//      In-place is safe: each thread reads AB[ch][pix] then writes the same
//      address; no other block touches that address.
// ---------------------------------------------------------------------------
__global__ __launch_bounds__(256) void k_vblur16(const float* __restrict__ HB,
                                                 float* __restrict__ AB) {
  const int tid = threadIdx.x;
  const int ch = blockIdx.z;
  const int x = blockIdx.x * 256 + tid;
  const int y0 = blockIdx.y * VT;
  float wg[NT];
  make_wg(wg);
  const float S = wsum(wg);

  float acc[VT];
#pragma unroll
  for (int t = 0; t < VT; ++t) acc[t] = 0.0f;
  const float* src = HB + ch * HWSZ;
#pragma unroll
  for (int r = 0; r < VT + 2 * RR; ++r) {
    const int yy = y0 - RR + r;
    float v = 0.0f;
    if (yy >= 0 && yy < HH) v = src[yy * WW + x];
#pragma unroll
    for (int t = 0; t < VT; ++t) {
      const int dy = r - t;
      if (dy >= 0 && dy < NT) acc[t] += wg[dy] * v;
    }
  }
  const float rowW = win_w(wg, S, x, WW);
  float* dst = AB + ch * HWSZ;
#pragma unroll
  for (int t = 0; t < VT; ++t) {
    const int y = y0 + t;
    const float colW = win_w(wg, S, y, HH);
    const int pix = y * WW + x;
    const float invN = 1.0f / (rowW * colW - 1.0f);
    const float center = dst[pix];
    dst[pix] = (acc[t] - center) * invN;
  }
}

// ---------------------------------------------------------------------------
// K5b: pointwise combine q_k = sum_c mean_a[c,k]*I_c + mean_b[k].
//      Grid (HW/256), block 256.
// ---------------------------------------------------------------------------
__global__ __launch_bounds__(256) void k_combine(const float* __restrict__ M2,
                                                 const float* __restrict__ I,
                                                 float* __restrict__ out) {
  const int i = blockIdx.x * 256 + threadIdx.x;
  float m[16];
#pragma unroll
  for (int ch = 0; ch < 16; ++ch) m[ch] = M2[ch * HWSZ + i];
  const float i0 = I[i * 3], i1 = I[i * 3 + 1], i2 = I[i * 3 + 2];
  float4 q;
  q.x = m[0] * i0 + m[4] * i1 + m[8] * i2 + m[12];
  q.y = m[1] * i0 + m[5] * i1 + m[9] * i2 + m[13];
  q.z = m[2] * i0 + m[6] * i1 + m[10] * i2 + m[14];
  q.w = m[3] * i0 + m[7] * i1 + m[11] * i2 + m[15];
  *reinterpret_cast<float4*>(out + (size_t)i * 4) = q;
}

extern "C" void kernel_launch(void* const* d_in, const int* in_sizes, int n_in,
                              void* d_out, int out_size, void* d_ws, size_t ws_size,
                              hipStream_t stream) {
  const float* I = (const float*)d_in[0];
  const float* P = (const float*)d_in[1];
  float* out = (float*)d_out;
  float* buf0 = (float*)d_ws;              // 25 planes
  float* buf1 = buf0 + 25 * (size_t)HWSZ;  // 25 planes

  for (int b = 0; b < 2; ++b) {
    const float* Ib = I + (size_t)b * HWSZ * 3;
    const float* Pb = P + (size_t)b * HWSZ * 4;
    float* outb = out + (size_t)b * HWSZ * 4;

    k_prod_hblur<<<dim3(WW / 256, HH), dim3(256), 0, stream>>>(Ib, Pb, buf0);
    k_vblur25<<<dim3(WW / 256, HH / VT, 25), dim3(256), 0, stream>>>(buf0, Ib, Pb, buf1);
    k_solve<<<dim3(HWSZ / 256), dim3(256), 0, stream>>>(buf1, buf0);
    k_hblur16<<<dim3(WW / 256, HH, 16), dim3(256), 0, stream>>>(buf0, buf1);
    k_vblur16<<<dim3(WW / 256, HH / VT, 16), dim3(256), 0, stream>>>(buf1, buf0);
    k_combine<<<dim3(HWSZ / 256), dim3(256), 0, stream>>>(buf0, Ib, outb);
  }
}